// Round 2
// 1202.848 us; speedup vs baseline: 1.5430x; 1.5430x over previous
//
#include <hip/hip_runtime.h>
#include <math.h>

#define H 64
#define NN 100000
#define EE 1000000
#define GG 64
#define TM 64
#define LDSP 68   // padded fp32 LDS row stride (floats) for non-edge kernels
#define EPB 128   // edges per block in edge_kernel
#define ALD 72    // padded bf16 LDS row stride (ushorts) in edge_kernel

typedef __attribute__((ext_vector_type(8))) short bf8;
typedef __attribute__((ext_vector_type(4))) float f32x4;

// ---------------------------------------------------------------------------
// helpers
// ---------------------------------------------------------------------------
__device__ __forceinline__ float gelu_f(float v) {
    return 0.5f * v * (1.0f + erff(v * 0.70710678118654752440f));
}

__device__ __forceinline__ unsigned short f2b(float f) {
    union { float f; unsigned int i; } x; x.f = f;
    unsigned int r = x.i + 0x7FFFu + ((x.i >> 16) & 1u);  // RNE
    return (unsigned short)(r >> 16);
}

__device__ __forceinline__ float b2f(unsigned short u) {
    union { unsigned int i; float f; } x; x.i = ((unsigned int)u) << 16; return x.f;
}

__device__ __forceinline__ void zero_acc(float acc[4][4]) {
    #pragma unroll
    for (int i = 0; i < 4; ++i)
        #pragma unroll
        for (int j = 0; j < 4; ++j) acc[i][j] = 0.0f;
}

// fp32 VALU GEMM tile (used by the small per-node/per-graph kernels)
__device__ __forceinline__ void gemm_tile(const float* __restrict__ W,
                                          const float* in_m,
                                          float acc[4][4], int m0, int j0) {
    #pragma unroll 4
    for (int k0 = 0; k0 < H; k0 += 4) {
        float4 A[4], B[4];
        #pragma unroll
        for (int mi = 0; mi < 4; ++mi)
            A[mi] = *(const float4*)(in_m + (m0 + mi) * LDSP + k0);
        #pragma unroll
        for (int kk = 0; kk < 4; ++kk)
            B[kk] = *(const float4*)(W + (k0 + kk) * H + j0);
        #pragma unroll
        for (int mi = 0; mi < 4; ++mi) {
            acc[mi][0] += A[mi].x * B[0].x + A[mi].y * B[1].x + A[mi].z * B[2].x + A[mi].w * B[3].x;
            acc[mi][1] += A[mi].x * B[0].y + A[mi].y * B[1].y + A[mi].z * B[2].y + A[mi].w * B[3].y;
            acc[mi][2] += A[mi].x * B[0].z + A[mi].y * B[1].z + A[mi].z * B[2].z + A[mi].w * B[3].z;
            acc[mi][3] += A[mi].x * B[0].w + A[mi].y * B[1].w + A[mi].z * B[2].w + A[mi].w * B[3].w;
        }
    }
}

__device__ __forceinline__ void store_tile_lds(float* in_m, const float acc[4][4],
                                               int m0, int j0) {
    #pragma unroll
    for (int mi = 0; mi < 4; ++mi)
        *(float4*)(in_m + (m0 + mi) * LDSP + j0) =
            make_float4(acc[mi][0], acc[mi][1], acc[mi][2], acc[mi][3]);
}

__device__ __forceinline__ void layernorm_rows(float acc[4][4],
                                               const float* __restrict__ g,
                                               const float* __restrict__ beta,
                                               int j0) {
    float4 g4 = *(const float4*)(g + j0);
    float4 b4 = *(const float4*)(beta + j0);
    float gj[4] = {g4.x, g4.y, g4.z, g4.w};
    float bj[4] = {b4.x, b4.y, b4.z, b4.w};
    #pragma unroll
    for (int mi = 0; mi < 4; ++mi) {
        float s = 0.f, q = 0.f;
        #pragma unroll
        for (int ji = 0; ji < 4; ++ji) { float v = acc[mi][ji]; s += v; q += v * v; }
        #pragma unroll
        for (int off = 1; off < 16; off <<= 1) {
            s += __shfl_xor(s, off, 64);
            q += __shfl_xor(q, off, 64);
        }
        float mu = s * (1.0f / 64.0f);
        float var = q * (1.0f / 64.0f) - mu * mu;
        float rs = rsqrtf(var + 1e-5f);
        #pragma unroll
        for (int ji = 0; ji < 4; ++ji)
            acc[mi][ji] = (acc[mi][ji] - mu) * rs * gj[ji] + bj[ji];
    }
}

// ---------------------------------------------------------------------------
// Weight prep: transpose 4 edge-pipeline weight blocks to bf16 Wt[j][k]
// stage 0: eW1 rows 128..191 (edge_attr part)   stage 1: eW2
// stage 2: n1W1 rows 64..127 (edge-feat part)   stage 3: n1W2
// ---------------------------------------------------------------------------
__global__ __launch_bounds__(256) void wprep_kernel(
    const float* __restrict__ eW1, const float* __restrict__ eW2,
    const float* __restrict__ n1W1, const float* __restrict__ n1W2,
    ushort* __restrict__ Wt) {
    int s = blockIdx.x;
    const float* src = (s == 0) ? (eW1 + 128 * H)
                     : (s == 1) ? eW2
                     : (s == 2) ? (n1W1 + 64 * H) : n1W2;
    int tid = threadIdx.x;
    #pragma unroll
    for (int p = 0; p < 16; ++p) {
        int idx = p * 256 + tid;
        int j = idx >> 6, k = idx & 63;
        Wt[s * 4096 + j * 64 + k] = f2b(src[k * H + j]);
    }
}

// ---------------------------------------------------------------------------
// Kernel B: per-graph tables  U_e = u@eW1[192:256] + eb1 ; U_n2 = u@n2W1[64:128] + n2b1
// ---------------------------------------------------------------------------
__global__ __launch_bounds__(256) void utab_kernel(
    const float* __restrict__ u,
    const float* __restrict__ eW1, const float* __restrict__ eb1,
    const float* __restrict__ n2W1, const float* __restrict__ n2b1,
    float* __restrict__ U_e, float* __restrict__ U_n2) {
    const float* W = (blockIdx.x == 0) ? (eW1 + 192 * H) : (n2W1 + 64 * H);
    const float* b = (blockIdx.x == 0) ? eb1 : n2b1;
    float* out = (blockIdx.x == 0) ? U_e : U_n2;
    int tid = threadIdx.x;
    for (int p = 0; p < 16; ++p) {
        int idx = p * 256 + tid;
        int g = idx >> 6, j = idx & 63;
        float s = b[j];
        for (int k = 0; k < H; ++k) s += u[g * H + k] * W[k * H + j];
        out[idx] = s;
    }
}

// ---------------------------------------------------------------------------
// Kernel A: per-node tables (bf16 outputs)
//   Q   = x @ eW1[0:64]   + U_e[batch[n]]
//   Pb  = x @ eW1[64:128]
//   Pn1 = x @ n1W1[0:64]  + n1b1
// ---------------------------------------------------------------------------
__global__ __launch_bounds__(256) void precompute_kernel(
    const float* __restrict__ x, const int* __restrict__ batch,
    const float* __restrict__ eW1, const float* __restrict__ n1W1,
    const float* __restrict__ n1b1, const float* __restrict__ U_e,
    ushort* __restrict__ Qb, ushort* __restrict__ Pbb,
    ushort* __restrict__ Pn1b) {
    __shared__ __align__(16) float in_m[TM * LDSP];
    __shared__ int bIdx[TM];
    int tid = threadIdx.x;
    int n0 = blockIdx.x * TM;
    int tx = tid & 15, ty = tid >> 4;
    int m0 = ty * 4, j0 = tx * 4;

    #pragma unroll
    for (int i = 0; i < 4; ++i) {
        int m = i * 16 + ty;
        int k = tx * 4;
        int n = n0 + m;
        float4 v = make_float4(0.f, 0.f, 0.f, 0.f);
        if (n < NN) v = *(const float4*)(x + (size_t)n * H + k);
        *(float4*)(in_m + m * LDSP + k) = v;
    }
    if (tid < TM) {
        int n = n0 + tid;
        bIdx[tid] = (n < NN) ? batch[n] : 0;
    }
    __syncthreads();

    float acc[4][4];
    // Q
    zero_acc(acc);
    gemm_tile(eW1, in_m, acc, m0, j0);
    #pragma unroll
    for (int mi = 0; mi < 4; ++mi) {
        int n = n0 + m0 + mi;
        if (n < NN) {
            float4 ue = *(const float4*)(U_e + bIdx[m0 + mi] * H + j0);
            ushort4 o = make_ushort4(f2b(acc[mi][0] + ue.x), f2b(acc[mi][1] + ue.y),
                                     f2b(acc[mi][2] + ue.z), f2b(acc[mi][3] + ue.w));
            *(ushort4*)(Qb + (size_t)n * H + j0) = o;
        }
    }
    // Pb
    zero_acc(acc);
    gemm_tile(eW1 + 64 * H, in_m, acc, m0, j0);
    #pragma unroll
    for (int mi = 0; mi < 4; ++mi) {
        int n = n0 + m0 + mi;
        if (n < NN) {
            ushort4 o = make_ushort4(f2b(acc[mi][0]), f2b(acc[mi][1]),
                                     f2b(acc[mi][2]), f2b(acc[mi][3]));
            *(ushort4*)(Pbb + (size_t)n * H + j0) = o;
        }
    }
    // Pn1
    zero_acc(acc);
    gemm_tile(n1W1, in_m, acc, m0, j0);
    {
        float4 b4 = *(const float4*)(n1b1 + j0);
        #pragma unroll
        for (int mi = 0; mi < 4; ++mi) {
            int n = n0 + m0 + mi;
            if (n < NN) {
                ushort4 o = make_ushort4(f2b(acc[mi][0] + b4.x), f2b(acc[mi][1] + b4.y),
                                         f2b(acc[mi][2] + b4.z), f2b(acc[mi][3] + b4.w));
                *(ushort4*)(Pn1b + (size_t)n * H + j0) = o;
            }
        }
    }
}

// ---------------------------------------------------------------------------
// Kernel C: fused per-edge pipeline, bf16 MFMA version.
// 128 edges/block, 4 waves; wave w owns rows [32w,32w+32) and all 64 cols.
// No __syncthreads anywhere: each wave only touches its own LDS rows, and
// DS ops within a wave complete in issue order.
// MFMA 16x16x32_bf16 layout: A[row=l&15][k=(l>>4)*8+e], B[k][col=l&15],
// C/D: col=l&15, row=(l>>4)*4+reg.
// ---------------------------------------------------------------------------
__global__ __launch_bounds__(256) void edge_kernel(
    const float* __restrict__ edge_attr, const int* __restrict__ ei,
    const ushort* __restrict__ Qb, const ushort* __restrict__ Pbb,
    const ushort* __restrict__ Pn1b, const ushort* __restrict__ Wt,
    const float* __restrict__ eb2, const float* __restrict__ eg,
    const float* __restrict__ ebt,
    const float* __restrict__ n1b2, const float* __restrict__ n1g,
    const float* __restrict__ n1bt,
    float* __restrict__ out_e, float* __restrict__ agg,
    float* __restrict__ deg) {
    __shared__ ushort A[EPB][ALD];
    const int tid = threadIdx.x;
    const int w = tid >> 6;
    const int l = tid & 63;
    const int q = l >> 4;
    const int i = l & 15;
    const int r0 = w * 32;                       // wave's row base in block
    const long long e0 = (long long)blockIdx.x * EPB;
    if (e0 + r0 >= EE) return;                   // EE % 32 == 0: wave-granular tail

    // ---- stage edge_attr rows [r0, r0+32) into LDS as bf16 ----
    #pragma unroll
    for (int t = 0; t < 4; ++t) {
        int linear = t * 512 + l * 8;            // 0..2047
        int row = linear >> 6;                   // 0..31
        int col = linear & 63;                   // multiple of 8
        const float* sp = edge_attr + (size_t)(e0 + r0 + row) * H + col;
        float4 v0 = *(const float4*)sp;
        float4 v1 = *(const float4*)(sp + 4);
        bf8 us;
        us[0] = (short)f2b(v0.x); us[1] = (short)f2b(v0.y);
        us[2] = (short)f2b(v0.z); us[3] = (short)f2b(v0.w);
        us[4] = (short)f2b(v1.x); us[5] = (short)f2b(v1.y);
        us[6] = (short)f2b(v1.z); us[7] = (short)f2b(v1.w);
        *(bf8*)(&A[r0 + row][col]) = us;
    }

    // ---- per-lane row indices (rows: mtl*16 + q*4 + r) ----
    int rb[8], cb[8];
    #pragma unroll
    for (int mtl = 0; mtl < 2; ++mtl)
        #pragma unroll
        for (int r = 0; r < 4; ++r) {
            long long erow = e0 + r0 + mtl * 16 + q * 4 + r;
            rb[mtl * 4 + r] = ei[erow] << 6;
            cb[mtl * 4 + r] = ei[EE + erow] << 6;
        }
    if (l < 32) atomicAdd(&deg[ei[e0 + r0 + l]], 1.0f);

    // ---- per-lane bias/gain columns (cols jt*16+i) ----
    float eb2c[4], egc[4], ebtc[4], nb2c[4], ngc[4], nbtc[4];
    #pragma unroll
    for (int jt = 0; jt < 4; ++jt) {
        int c = jt * 16 + i;
        eb2c[jt] = eb2[c]; egc[jt] = eg[c]; ebtc[jt] = ebt[c];
        nb2c[jt] = n1b2[c]; ngc[jt] = n1g[c]; nbtc[jt] = n1bt[c];
    }

    f32x4 acc[2][4];
    auto zacc = [&]() {
        #pragma unroll
        for (int m = 0; m < 2; ++m)
            #pragma unroll
            for (int jt = 0; jt < 4; ++jt)
                acc[m][jt] = (f32x4){0.f, 0.f, 0.f, 0.f};
    };
    auto mm = [&](const ushort* Ws) {
        #pragma unroll
        for (int kb = 0; kb < 2; ++kb) {
            bf8 af0 = *(const bf8*)(&A[r0 + i][kb * 32 + q * 8]);
            bf8 af1 = *(const bf8*)(&A[r0 + 16 + i][kb * 32 + q * 8]);
            #pragma unroll
            for (int jt = 0; jt < 4; ++jt) {
                bf8 bf = *(const bf8*)(Ws + (jt * 16 + i) * 64 + kb * 32 + q * 8);
                acc[0][jt] = __builtin_amdgcn_mfma_f32_16x16x32_bf16(af0, bf, acc[0][jt], 0, 0, 0);
                acc[1][jt] = __builtin_amdgcn_mfma_f32_16x16x32_bf16(af1, bf, acc[1][jt], 0, 0, 0);
            }
        }
    };

    // ---- stage 1: h1 = gelu(ea@W1c + Q[row] + Pb[col]) ----
    zacc(); mm(Wt);
    #pragma unroll
    for (int mtl = 0; mtl < 2; ++mtl)
        #pragma unroll
        for (int r = 0; r < 4; ++r) {
            int row = r0 + mtl * 16 + q * 4 + r;
            int rbase = rb[mtl * 4 + r], cbase = cb[mtl * 4 + r];
            #pragma unroll
            for (int jt = 0; jt < 4; ++jt) {
                int c = jt * 16 + i;
                float v = acc[mtl][jt][r] + b2f(Qb[rbase + c]) + b2f(Pbb[cbase + c]);
                A[row][c] = f2b(gelu_f(v));
            }
        }

    // ---- stage 2: en = LN(gelu(h1@eW2 + eb2))*eg + ebt ; write out_e ----
    zacc(); mm(Wt + 4096);
    #pragma unroll
    for (int mtl = 0; mtl < 2; ++mtl)
        #pragma unroll
        for (int jt = 0; jt < 4; ++jt)
            #pragma unroll
            for (int r = 0; r < 4; ++r)
                acc[mtl][jt][r] = gelu_f(acc[mtl][jt][r] + eb2c[jt]);
    #pragma unroll
    for (int mtl = 0; mtl < 2; ++mtl)
        #pragma unroll
        for (int r = 0; r < 4; ++r) {
            float s = 0.f, ss = 0.f;
            #pragma unroll
            for (int jt = 0; jt < 4; ++jt) { float v = acc[mtl][jt][r]; s += v; ss += v * v; }
            #pragma unroll
            for (int off = 1; off < 16; off <<= 1) {
                s += __shfl_xor(s, off, 64);
                ss += __shfl_xor(ss, off, 64);
            }
            float mu = s * 0.015625f;
            float rs = rsqrtf(ss * 0.015625f - mu * mu + 1e-5f);
            int row = r0 + mtl * 16 + q * 4 + r;
            float* op = out_e + (size_t)(e0 + row) * H;
            #pragma unroll
            for (int jt = 0; jt < 4; ++jt) {
                int c = jt * 16 + i;
                float v = (acc[mtl][jt][r] - mu) * rs * egc[jt] + ebtc[jt];
                op[c] = v;
                A[row][c] = f2b(v);
            }
        }

    // ---- stage 3: t1 = gelu(en@n1W1b + Pn1[col]) ----
    zacc(); mm(Wt + 8192);
    #pragma unroll
    for (int mtl = 0; mtl < 2; ++mtl)
        #pragma unroll
        for (int r = 0; r < 4; ++r) {
            int row = r0 + mtl * 16 + q * 4 + r;
            int cbase = cb[mtl * 4 + r];
            #pragma unroll
            for (int jt = 0; jt < 4; ++jt) {
                int c = jt * 16 + i;
                float v = acc[mtl][jt][r] + b2f(Pn1b[cbase + c]);
                A[row][c] = f2b(gelu_f(v));
            }
        }

    // ---- stage 4: msg = LN(gelu(t1@n1W2 + n1b2))*n1g + n1bt ; scatter ----
    zacc(); mm(Wt + 12288);
    #pragma unroll
    for (int mtl = 0; mtl < 2; ++mtl)
        #pragma unroll
        for (int jt = 0; jt < 4; ++jt)
            #pragma unroll
            for (int r = 0; r < 4; ++r)
                acc[mtl][jt][r] = gelu_f(acc[mtl][jt][r] + nb2c[jt]);
    #pragma unroll
    for (int mtl = 0; mtl < 2; ++mtl)
        #pragma unroll
        for (int r = 0; r < 4; ++r) {
            float s = 0.f, ss = 0.f;
            #pragma unroll
            for (int jt = 0; jt < 4; ++jt) { float v = acc[mtl][jt][r]; s += v; ss += v * v; }
            #pragma unroll
            for (int off = 1; off < 16; off <<= 1) {
                s += __shfl_xor(s, off, 64);
                ss += __shfl_xor(ss, off, 64);
            }
            float mu = s * 0.015625f;
            float rs = rsqrtf(ss * 0.015625f - mu * mu + 1e-5f);
            int rbase = rb[mtl * 4 + r];
            #pragma unroll
            for (int jt = 0; jt < 4; ++jt) {
                int c = jt * 16 + i;
                float v = (acc[mtl][jt][r] - mu) * rs * ngc[jt] + nbtc[jt];
                atomicAdd(&agg[rbase + c], v);
            }
        }
}

// ---------------------------------------------------------------------------
// Kernel D: node update + scatter into global sums.
// g_sum/g_cnt are accumulated with a per-block segmented reduction first
// (batch is sorted, so a 64-row tile spans ~1-2 graphs): one atomicAdd per
// column per segment per block instead of one per element.  This removes the
// 6.4M same-address atomics that made this kernel 715us.
// ---------------------------------------------------------------------------
__global__ __launch_bounds__(256) void node_kernel(
    const float* __restrict__ agg_sum, const float* __restrict__ deg,
    const int* __restrict__ batch, const float* __restrict__ U_n2,
    const float* __restrict__ n2W1a, const float* __restrict__ n2W2,
    const float* __restrict__ n2b2, const float* __restrict__ n2g,
    const float* __restrict__ n2beta,
    float* __restrict__ out_x, float* __restrict__ g_sum,
    float* __restrict__ g_cnt) {
    __shared__ __align__(16) float in_m[TM * LDSP];
    __shared__ int bIdx[TM];
    int tid = threadIdx.x;
    int n0 = blockIdx.x * TM;
    int tx = tid & 15, ty = tid >> 4;
    int m0 = ty * 4, j0 = tx * 4;
    int valid = NN - n0; if (valid > TM) valid = TM;

    if (tid < TM) {
        int n = n0 + tid;
        bIdx[tid] = (n < NN) ? batch[n] : 0;
    }
    #pragma unroll
    for (int i = 0; i < 4; ++i) {
        int m = i * 16 + ty;
        int k = tx * 4;
        int n = n0 + m;
        float4 v = make_float4(0.f, 0.f, 0.f, 0.f);
        if (n < NN) {
            v = *(const float4*)(agg_sum + (size_t)n * H + k);
            float inv = 1.0f / fmaxf(deg[n], 1.0f);
            v.x *= inv; v.y *= inv; v.z *= inv; v.w *= inv;
        }
        *(float4*)(in_m + m * LDSP + k) = v;
    }
    __syncthreads();

    float acc[4][4];
    zero_acc(acc);
    gemm_tile(n2W1a, in_m, acc, m0, j0);
    #pragma unroll
    for (int mi = 0; mi < 4; ++mi) {
        float4 ue = *(const float4*)(U_n2 + bIdx[m0 + mi] * H + j0);
        acc[mi][0] = gelu_f(acc[mi][0] + ue.x);
        acc[mi][1] = gelu_f(acc[mi][1] + ue.y);
        acc[mi][2] = gelu_f(acc[mi][2] + ue.z);
        acc[mi][3] = gelu_f(acc[mi][3] + ue.w);
    }
    __syncthreads();
    store_tile_lds(in_m, acc, m0, j0);
    __syncthreads();

    zero_acc(acc);
    gemm_tile(n2W2, in_m, acc, m0, j0);
    {
        float4 b4 = *(const float4*)(n2b2 + j0);
        float bb[4] = {b4.x, b4.y, b4.z, b4.w};
        #pragma unroll
        for (int mi = 0; mi < 4; ++mi)
            #pragma unroll
            for (int ji = 0; ji < 4; ++ji)
                acc[mi][ji] = gelu_f(acc[mi][ji] + bb[ji]);
    }
    layernorm_rows(acc, n2g, n2beta, j0);
    #pragma unroll
    for (int mi = 0; mi < 4; ++mi) {
        int n = n0 + m0 + mi;
        if (n < NN) {
            *(float4*)(out_x + (size_t)n * H + j0) =
                make_float4(acc[mi][0], acc[mi][1], acc[mi][2], acc[mi][3]);
        }
    }

    // ---- per-block segmented reduction into g_sum / g_cnt ----
    int b_lo = bIdx[0];
    int b_hi = bIdx[valid - 1];
    for (int b = b_lo; b <= b_hi; ++b) {
        float p0 = 0.f, p1 = 0.f, p2 = 0.f, p3 = 0.f;
        #pragma unroll
        for (int mi = 0; mi < 4; ++mi) {
            int m = m0 + mi;
            if (m < valid && bIdx[m] == b) {
                p0 += acc[mi][0]; p1 += acc[mi][1];
                p2 += acc[mi][2]; p3 += acc[mi][3];
            }
        }
        __syncthreads();   // previous users of in_m (gemm reads / prior b reads) done
        *(float4*)(in_m + ty * LDSP + j0) = make_float4(p0, p1, p2, p3);
        __syncthreads();
        if (tid < H) {
            float s = 0.f;
            #pragma unroll
            for (int r = 0; r < 16; ++r) s += in_m[r * LDSP + tid];
            atomicAdd(&g_sum[(size_t)b * H + tid], s);
        } else if (tid == H) {
            int c = 0;
            for (int m = 0; m < valid; ++m) c += (bIdx[m] == b) ? 1 : 0;
            atomicAdd(&g_cnt[b], (float)c);
        }
    }
}

// ---------------------------------------------------------------------------
// Kernel E: global model (single block)
// ---------------------------------------------------------------------------
__global__ __launch_bounds__(256) void global_kernel(
    const float* __restrict__ u, const float* __restrict__ g_sum,
    const float* __restrict__ g_cnt,
    const float* __restrict__ gW1, const float* __restrict__ gb1,
    const float* __restrict__ gW2, const float* __restrict__ gb2,
    const float* __restrict__ gg, const float* __restrict__ gbeta,
    float* __restrict__ out_u) {
    __shared__ __align__(16) float in_m[TM * LDSP];
    int tid = threadIdx.x;
    int tx = tid & 15, ty = tid >> 4;
    int m0 = ty * 4, j0 = tx * 4;

    #pragma unroll
    for (int i = 0; i < 4; ++i) {
        int m = i * 16 + ty;
        int k = tx * 4;
        *(float4*)(in_m + m * LDSP + k) = *(const float4*)(u + m * H + k);
    }
    __syncthreads();

    float acc[4][4];
    zero_acc(acc);
    gemm_tile(gW1, in_m, acc, m0, j0);
    __syncthreads();
    #pragma unroll
    for (int i = 0; i < 4; ++i) {
        int m = i * 16 + ty;
        int k = tx * 4;
        float4 v = *(const float4*)(g_sum + m * H + k);
        float inv = 1.0f / fmaxf(g_cnt[m], 1.0f);
        v.x *= inv; v.y *= inv; v.z *= inv; v.w *= inv;
        *(float4*)(in_m + m * LDSP + k) = v;
    }
    __syncthreads();
    gemm_tile(gW1 + 64 * H, in_m, acc, m0, j0);
    {
        float4 b4 = *(const float4*)(gb1 + j0);
        float bb[4] = {b4.x, b4.y, b4.z, b4.w};
        #pragma unroll
        for (int mi = 0; mi < 4; ++mi)
            #pragma unroll
            for (int ji = 0; ji < 4; ++ji)
                acc[mi][ji] = gelu_f(acc[mi][ji] + bb[ji]);
    }
    __syncthreads();
    store_tile_lds(in_m, acc, m0, j0);
    __syncthreads();

    zero_acc(acc);
    gemm_tile(gW2, in_m, acc, m0, j0);
    {
        float4 b4 = *(const float4*)(gb2 + j0);
        float bb[4] = {b4.x, b4.y, b4.z, b4.w};
        #pragma unroll
        for (int mi = 0; mi < 4; ++mi)
            #pragma unroll
            for (int ji = 0; ji < 4; ++ji)
                acc[mi][ji] = gelu_f(acc[mi][ji] + bb[ji]);
    }
    layernorm_rows(acc, gg, gbeta, j0);
    #pragma unroll
    for (int mi = 0; mi < 4; ++mi)
        *(float4*)(out_u + (m0 + mi) * H + j0) =
            make_float4(acc[mi][0], acc[mi][1], acc[mi][2], acc[mi][3]);
}

// ---------------------------------------------------------------------------
extern "C" void kernel_launch(void* const* d_in, const int* in_sizes, int n_in,
                              void* d_out, int out_size, void* d_ws, size_t ws_size,
                              hipStream_t stream) {
    const float* x         = (const float*)d_in[0];
    const int*   ei        = (const int*)d_in[1];
    const float* edge_attr = (const float*)d_in[2];
    const float* u         = (const float*)d_in[3];
    const int*   batch     = (const int*)d_in[4];
    const float* eW1 = (const float*)d_in[5];
    const float* eb1 = (const float*)d_in[6];
    const float* eW2 = (const float*)d_in[7];
    const float* eb2 = (const float*)d_in[8];
    const float* eg  = (const float*)d_in[9];
    const float* ebt = (const float*)d_in[10];
    const float* n1W1 = (const float*)d_in[11];
    const float* n1b1 = (const float*)d_in[12];
    const float* n1W2 = (const float*)d_in[13];
    const float* n1b2 = (const float*)d_in[14];
    const float* n1g  = (const float*)d_in[15];
    const float* n1bt = (const float*)d_in[16];
    const float* n2W1 = (const float*)d_in[17];
    const float* n2b1 = (const float*)d_in[18];
    const float* n2W2 = (const float*)d_in[19];
    const float* n2b2 = (const float*)d_in[20];
    const float* n2g  = (const float*)d_in[21];
    const float* n2bt = (const float*)d_in[22];
    const float* gW1 = (const float*)d_in[23];
    const float* gb1 = (const float*)d_in[24];
    const float* gW2 = (const float*)d_in[25];
    const float* gb2 = (const float*)d_in[26];
    const float* gg  = (const float*)d_in[27];
    const float* gbt = (const float*)d_in[28];

    ushort* Qb   = (ushort*)d_ws;
    ushort* Pbb  = Qb + (size_t)NN * H;
    ushort* Pn1b = Pbb + (size_t)NN * H;
    ushort* Wt   = Pn1b + (size_t)NN * H;
    float* U_e   = (float*)(Wt + 4 * 4096);
    float* U_n2  = U_e + GG * H;
    float* agg   = U_n2 + GG * H;            // ---- zeroed region starts here
    float* deg   = agg + (size_t)NN * H;
    float* gsum  = deg + NN;
    float* gcnt  = gsum + GG * H;
    size_t zcount = (size_t)NN * H + NN + GG * H + GG;

    hipMemsetAsync(agg, 0, zcount * sizeof(float), stream);

    float* out_x = (float*)d_out;
    float* out_e = out_x + (size_t)NN * H;
    float* out_u = out_e + (size_t)EE * H;

    wprep_kernel<<<4, 256, 0, stream>>>(eW1, eW2, n1W1, n1W2, Wt);
    utab_kernel<<<2, 256, 0, stream>>>(u, eW1, eb1, n2W1, n2b1, U_e, U_n2);
    precompute_kernel<<<(NN + TM - 1) / TM, 256, 0, stream>>>(
        x, batch, eW1, n1W1, n1b1, U_e, Qb, Pbb, Pn1b);
    edge_kernel<<<(EE + EPB - 1) / EPB, 256, 0, stream>>>(
        edge_attr, ei, Qb, Pbb, Pn1b, Wt,
        eb2, eg, ebt, n1b2, n1g, n1bt,
        out_e, agg, deg);
    node_kernel<<<(NN + TM - 1) / TM, 256, 0, stream>>>(
        agg, deg, batch, U_n2, n2W1, n2W2, n2b2, n2g, n2bt,
        out_x, gsum, gcnt);
    global_kernel<<<1, 256, 0, stream>>>(
        u, gsum, gcnt, gW1, gb1, gW2, gb2, gg, gbt, out_u);
}

// Round 3
// 1038.407 us; speedup vs baseline: 1.7873x; 1.1584x over previous
//
#include <hip/hip_runtime.h>
#include <math.h>

#define H 64
#define NN 100000
#define EE 1000000
#define GG 64
#define TM 64
#define LDSP 68   // padded fp32 LDS row stride (floats) for non-edge kernels
#define EPB 128   // edges per block in edge_kernel
#define ALD 72    // padded bf16 LDS row stride (ushorts) in edge_kernel

typedef __attribute__((ext_vector_type(8))) short bf8;
typedef __attribute__((ext_vector_type(4))) float f32x4;

// ---------------------------------------------------------------------------
// helpers
// ---------------------------------------------------------------------------
__device__ __forceinline__ float gelu_f(float v) {
    return 0.5f * v * (1.0f + erff(v * 0.70710678118654752440f));
}

__device__ __forceinline__ unsigned short f2b(float f) {
    union { float f; unsigned int i; } x; x.f = f;
    unsigned int r = x.i + 0x7FFFu + ((x.i >> 16) & 1u);  // RNE
    return (unsigned short)(r >> 16);
}

__device__ __forceinline__ float b2f(unsigned short u) {
    union { unsigned int i; float f; } x; x.i = ((unsigned int)u) << 16; return x.f;
}

__device__ __forceinline__ void zero_acc(float acc[4][4]) {
    #pragma unroll
    for (int i = 0; i < 4; ++i)
        #pragma unroll
        for (int j = 0; j < 4; ++j) acc[i][j] = 0.0f;
}

// fp32 VALU GEMM tile (used by the small per-node/per-graph kernels)
__device__ __forceinline__ void gemm_tile(const float* __restrict__ W,
                                          const float* in_m,
                                          float acc[4][4], int m0, int j0) {
    #pragma unroll 4
    for (int k0 = 0; k0 < H; k0 += 4) {
        float4 A[4], B[4];
        #pragma unroll
        for (int mi = 0; mi < 4; ++mi)
            A[mi] = *(const float4*)(in_m + (m0 + mi) * LDSP + k0);
        #pragma unroll
        for (int kk = 0; kk < 4; ++kk)
            B[kk] = *(const float4*)(W + (k0 + kk) * H + j0);
        #pragma unroll
        for (int mi = 0; mi < 4; ++mi) {
            acc[mi][0] += A[mi].x * B[0].x + A[mi].y * B[1].x + A[mi].z * B[2].x + A[mi].w * B[3].x;
            acc[mi][1] += A[mi].x * B[0].y + A[mi].y * B[1].y + A[mi].z * B[2].y + A[mi].w * B[3].y;
            acc[mi][2] += A[mi].x * B[0].z + A[mi].y * B[1].z + A[mi].z * B[2].z + A[mi].w * B[3].z;
            acc[mi][3] += A[mi].x * B[0].w + A[mi].y * B[1].w + A[mi].z * B[2].w + A[mi].w * B[3].w;
        }
    }
}

__device__ __forceinline__ void store_tile_lds(float* in_m, const float acc[4][4],
                                               int m0, int j0) {
    #pragma unroll
    for (int mi = 0; mi < 4; ++mi)
        *(float4*)(in_m + (m0 + mi) * LDSP + j0) =
            make_float4(acc[mi][0], acc[mi][1], acc[mi][2], acc[mi][3]);
}

__device__ __forceinline__ void layernorm_rows(float acc[4][4],
                                               const float* __restrict__ g,
                                               const float* __restrict__ beta,
                                               int j0) {
    float4 g4 = *(const float4*)(g + j0);
    float4 b4 = *(const float4*)(beta + j0);
    float gj[4] = {g4.x, g4.y, g4.z, g4.w};
    float bj[4] = {b4.x, b4.y, b4.z, b4.w};
    #pragma unroll
    for (int mi = 0; mi < 4; ++mi) {
        float s = 0.f, q = 0.f;
        #pragma unroll
        for (int ji = 0; ji < 4; ++ji) { float v = acc[mi][ji]; s += v; q += v * v; }
        #pragma unroll
        for (int off = 1; off < 16; off <<= 1) {
            s += __shfl_xor(s, off, 64);
            q += __shfl_xor(q, off, 64);
        }
        float mu = s * (1.0f / 64.0f);
        float var = q * (1.0f / 64.0f) - mu * mu;
        float rs = rsqrtf(var + 1e-5f);
        #pragma unroll
        for (int ji = 0; ji < 4; ++ji)
            acc[mi][ji] = (acc[mi][ji] - mu) * rs * gj[ji] + bj[ji];
    }
}

// ---------------------------------------------------------------------------
// Weight prep: transpose 4 edge-pipeline weight blocks to bf16 Wt[j][k]
// ---------------------------------------------------------------------------
__global__ __launch_bounds__(256) void wprep_kernel(
    const float* __restrict__ eW1, const float* __restrict__ eW2,
    const float* __restrict__ n1W1, const float* __restrict__ n1W2,
    ushort* __restrict__ Wt) {
    int s = blockIdx.x;
    const float* src = (s == 0) ? (eW1 + 128 * H)
                     : (s == 1) ? eW2
                     : (s == 2) ? (n1W1 + 64 * H) : n1W2;
    int tid = threadIdx.x;
    #pragma unroll
    for (int p = 0; p < 16; ++p) {
        int idx = p * 256 + tid;
        int j = idx >> 6, k = idx & 63;
        Wt[s * 4096 + j * 64 + k] = f2b(src[k * H + j]);
    }
}

// ---------------------------------------------------------------------------
// Kernel B: per-graph tables  U_e = u@eW1[192:256] + eb1 ; U_n2 = u@n2W1[64:128] + n2b1
// ---------------------------------------------------------------------------
__global__ __launch_bounds__(256) void utab_kernel(
    const float* __restrict__ u,
    const float* __restrict__ eW1, const float* __restrict__ eb1,
    const float* __restrict__ n2W1, const float* __restrict__ n2b1,
    float* __restrict__ U_e, float* __restrict__ U_n2) {
    const float* W = (blockIdx.x == 0) ? (eW1 + 192 * H) : (n2W1 + 64 * H);
    const float* b = (blockIdx.x == 0) ? eb1 : n2b1;
    float* out = (blockIdx.x == 0) ? U_e : U_n2;
    int tid = threadIdx.x;
    for (int p = 0; p < 16; ++p) {
        int idx = p * 256 + tid;
        int g = idx >> 6, j = idx & 63;
        float s = b[j];
        for (int k = 0; k < H; ++k) s += u[g * H + k] * W[k * H + j];
        out[idx] = s;
    }
}

// ---------------------------------------------------------------------------
// Kernel A: per-node tables (bf16 outputs), PERMUTED layout:
//   table[node][ (c&15)*4 + (c>>4) ] = value at original column c.
// An edge_kernel lane (lane&15 == i) then reads its 4 needed columns
// {jt*16+i} as one contiguous ushort4 at offset i*4.
//   Q   = x @ eW1[0:64]   + U_e[batch[n]]
//   Pb  = x @ eW1[64:128]
//   Pn1 = x @ n1W1[0:64]  + n1b1
// ---------------------------------------------------------------------------
__global__ __launch_bounds__(256) void precompute_kernel(
    const float* __restrict__ x, const int* __restrict__ batch,
    const float* __restrict__ eW1, const float* __restrict__ n1W1,
    const float* __restrict__ n1b1, const float* __restrict__ U_e,
    ushort* __restrict__ Qb, ushort* __restrict__ Pbb,
    ushort* __restrict__ Pn1b) {
    __shared__ __align__(16) float in_m[TM * LDSP];
    __shared__ int bIdx[TM];
    int tid = threadIdx.x;
    int n0 = blockIdx.x * TM;
    int tx = tid & 15, ty = tid >> 4;
    int m0 = ty * 4, j0 = tx * 4;

    #pragma unroll
    for (int i = 0; i < 4; ++i) {
        int m = i * 16 + ty;
        int k = tx * 4;
        int n = n0 + m;
        float4 v = make_float4(0.f, 0.f, 0.f, 0.f);
        if (n < NN) v = *(const float4*)(x + (size_t)n * H + k);
        *(float4*)(in_m + m * LDSP + k) = v;
    }
    if (tid < TM) {
        int n = n0 + tid;
        bIdx[tid] = (n < NN) ? batch[n] : 0;
    }
    __syncthreads();

    // permuted position for original column c
    auto pp = [](int c) { return ((c & 15) << 2) | (c >> 4); };

    float acc[4][4];
    // Q
    zero_acc(acc);
    gemm_tile(eW1, in_m, acc, m0, j0);
    #pragma unroll
    for (int mi = 0; mi < 4; ++mi) {
        int n = n0 + m0 + mi;
        if (n < NN) {
            float4 ue = *(const float4*)(U_e + bIdx[m0 + mi] * H + j0);
            float uearr[4] = {ue.x, ue.y, ue.z, ue.w};
            #pragma unroll
            for (int ji = 0; ji < 4; ++ji)
                Qb[(size_t)n * H + pp(j0 + ji)] = f2b(acc[mi][ji] + uearr[ji]);
        }
    }
    // Pb
    zero_acc(acc);
    gemm_tile(eW1 + 64 * H, in_m, acc, m0, j0);
    #pragma unroll
    for (int mi = 0; mi < 4; ++mi) {
        int n = n0 + m0 + mi;
        if (n < NN) {
            #pragma unroll
            for (int ji = 0; ji < 4; ++ji)
                Pbb[(size_t)n * H + pp(j0 + ji)] = f2b(acc[mi][ji]);
        }
    }
    // Pn1
    zero_acc(acc);
    gemm_tile(n1W1, in_m, acc, m0, j0);
    {
        float4 b4 = *(const float4*)(n1b1 + j0);
        float bb[4] = {b4.x, b4.y, b4.z, b4.w};
        #pragma unroll
        for (int mi = 0; mi < 4; ++mi) {
            int n = n0 + m0 + mi;
            if (n < NN) {
                #pragma unroll
                for (int ji = 0; ji < 4; ++ji)
                    Pn1b[(size_t)n * H + pp(j0 + ji)] = f2b(acc[mi][ji] + bb[ji]);
            }
        }
    }
}

// ---------------------------------------------------------------------------
// Kernel C: fused per-edge pipeline, bf16 MFMA version.
// 128 edges/block, 4 waves; wave w owns rows [32w,32w+32) and all 64 cols.
// No __syncthreads anywhere: each wave only touches its own LDS rows.
// Gathers of the permuted node tables are issued as ushort4 row-loads,
// software-pipelined ahead of the MFMA stages that hide their latency.
// MFMA 16x16x32_bf16 layout: A[row=l&15][k=(l>>4)*8+e], B[k][col=l&15],
// C/D: col=l&15, row=(l>>4)*4+reg.
// ---------------------------------------------------------------------------
__global__ __launch_bounds__(256) void edge_kernel(
    const float* __restrict__ edge_attr, const int* __restrict__ ei,
    const ushort* __restrict__ Qb, const ushort* __restrict__ Pbb,
    const ushort* __restrict__ Pn1b, const ushort* __restrict__ Wt,
    const float* __restrict__ eb2, const float* __restrict__ eg,
    const float* __restrict__ ebt,
    const float* __restrict__ n1b2, const float* __restrict__ n1g,
    const float* __restrict__ n1bt,
    float* __restrict__ out_e, float* __restrict__ agg,
    float* __restrict__ deg) {
    __shared__ ushort A[EPB][ALD];
    const int tid = threadIdx.x;
    const int w = tid >> 6;
    const int l = tid & 63;
    const int q = l >> 4;
    const int i = l & 15;
    const int r0 = w * 32;                       // wave's row base in block
    const long long e0 = (long long)blockIdx.x * EPB;
    if (e0 + r0 >= EE) return;                   // EE % 32 == 0: wave-granular tail

    // ---- vectorized index loads (issued first; 4x int4 instead of 16 scalar)
    // rows handled by this lane: mtl*16 + q*4 + r  (r = 0..3)
    int rb[8], cb[8];
    {
        int4 ra0 = *(const int4*)(ei + e0 + r0 + q * 4);
        int4 ra1 = *(const int4*)(ei + e0 + r0 + 16 + q * 4);
        int4 ca0 = *(const int4*)(ei + EE + e0 + r0 + q * 4);
        int4 ca1 = *(const int4*)(ei + EE + e0 + r0 + 16 + q * 4);
        rb[0] = ra0.x << 6; rb[1] = ra0.y << 6; rb[2] = ra0.z << 6; rb[3] = ra0.w << 6;
        rb[4] = ra1.x << 6; rb[5] = ra1.y << 6; rb[6] = ra1.z << 6; rb[7] = ra1.w << 6;
        cb[0] = ca0.x << 6; cb[1] = ca0.y << 6; cb[2] = ca0.z << 6; cb[3] = ca0.w << 6;
        cb[4] = ca1.x << 6; cb[5] = ca1.y << 6; cb[6] = ca1.z << 6; cb[7] = ca1.w << 6;
    }

    // ---- stage edge_attr rows [r0, r0+32) into LDS as bf16 ----
    #pragma unroll
    for (int t = 0; t < 4; ++t) {
        int linear = t * 512 + l * 8;            // 0..2047
        int row = linear >> 6;                   // 0..31
        int col = linear & 63;                   // multiple of 8
        const float* sp = edge_attr + (size_t)(e0 + r0 + row) * H + col;
        float4 v0 = *(const float4*)sp;
        float4 v1 = *(const float4*)(sp + 4);
        bf8 us;
        us[0] = (short)f2b(v0.x); us[1] = (short)f2b(v0.y);
        us[2] = (short)f2b(v0.z); us[3] = (short)f2b(v0.w);
        us[4] = (short)f2b(v1.x); us[5] = (short)f2b(v1.y);
        us[6] = (short)f2b(v1.z); us[7] = (short)f2b(v1.w);
        *(bf8*)(&A[r0 + row][col]) = us;
    }

    // ---- prefetch stage-1 table rows (permuted: ushort4 per row per table).
    // Independent of the MFMA below; latency hides under staging + stage-1 mm.
    ushort4 qv[8], pv[8];
    #pragma unroll
    for (int rr = 0; rr < 8; ++rr) {
        qv[rr] = *(const ushort4*)(Qb + rb[rr] + i * 4);
        pv[rr] = *(const ushort4*)(Pbb + cb[rr] + i * 4);
    }

    if (l < 32) atomicAdd(&deg[ei[e0 + r0 + l]], 1.0f);

    // ---- per-lane bias/gain columns (cols jt*16+i) ----
    float eb2c[4], egc[4], ebtc[4], nb2c[4], ngc[4], nbtc[4];
    #pragma unroll
    for (int jt = 0; jt < 4; ++jt) {
        int c = jt * 16 + i;
        eb2c[jt] = eb2[c]; egc[jt] = eg[c]; ebtc[jt] = ebt[c];
        nb2c[jt] = n1b2[c]; ngc[jt] = n1g[c]; nbtc[jt] = n1bt[c];
    }

    f32x4 acc[2][4];
    auto zacc = [&]() {
        #pragma unroll
        for (int m = 0; m < 2; ++m)
            #pragma unroll
            for (int jt = 0; jt < 4; ++jt)
                acc[m][jt] = (f32x4){0.f, 0.f, 0.f, 0.f};
    };
    auto mm = [&](const ushort* Ws) {
        #pragma unroll
        for (int kb = 0; kb < 2; ++kb) {
            bf8 af0 = *(const bf8*)(&A[r0 + i][kb * 32 + q * 8]);
            bf8 af1 = *(const bf8*)(&A[r0 + 16 + i][kb * 32 + q * 8]);
            #pragma unroll
            for (int jt = 0; jt < 4; ++jt) {
                bf8 bf = *(const bf8*)(Ws + (jt * 16 + i) * 64 + kb * 32 + q * 8);
                acc[0][jt] = __builtin_amdgcn_mfma_f32_16x16x32_bf16(af0, bf, acc[0][jt], 0, 0, 0);
                acc[1][jt] = __builtin_amdgcn_mfma_f32_16x16x32_bf16(af1, bf, acc[1][jt], 0, 0, 0);
            }
        }
    };

    // ---- stage 1: h1 = gelu(ea@W1c + Q[row] + Pb[col]) ----
    zacc(); mm(Wt);
    #pragma unroll
    for (int mtl = 0; mtl < 2; ++mtl)
        #pragma unroll
        for (int r = 0; r < 4; ++r) {
            int rr = mtl * 4 + r;
            int row = r0 + mtl * 16 + q * 4 + r;
            const ushort* qp = (const ushort*)&qv[rr];
            const ushort* pb = (const ushort*)&pv[rr];
            #pragma unroll
            for (int jt = 0; jt < 4; ++jt) {
                int c = jt * 16 + i;
                float v = acc[mtl][jt][r] + b2f(qp[jt]) + b2f(pb[jt]);
                A[row][c] = f2b(gelu_f(v));
            }
        }

    // ---- prefetch stage-3 table rows; hidden under stage-2 mm + LN ----
    ushort4 nv[8];
    #pragma unroll
    for (int rr = 0; rr < 8; ++rr)
        nv[rr] = *(const ushort4*)(Pn1b + cb[rr] + i * 4);

    // ---- stage 2: en = LN(gelu(h1@eW2 + eb2))*eg + ebt ; write out_e ----
    zacc(); mm(Wt + 4096);
    #pragma unroll
    for (int mtl = 0; mtl < 2; ++mtl)
        #pragma unroll
        for (int jt = 0; jt < 4; ++jt)
            #pragma unroll
            for (int r = 0; r < 4; ++r)
                acc[mtl][jt][r] = gelu_f(acc[mtl][jt][r] + eb2c[jt]);
    #pragma unroll
    for (int mtl = 0; mtl < 2; ++mtl)
        #pragma unroll
        for (int r = 0; r < 4; ++r) {
            float s = 0.f, ss = 0.f;
            #pragma unroll
            for (int jt = 0; jt < 4; ++jt) { float v = acc[mtl][jt][r]; s += v; ss += v * v; }
            #pragma unroll
            for (int off = 1; off < 16; off <<= 1) {
                s += __shfl_xor(s, off, 64);
                ss += __shfl_xor(ss, off, 64);
            }
            float mu = s * 0.015625f;
            float rs = rsqrtf(ss * 0.015625f - mu * mu + 1e-5f);
            int row = r0 + mtl * 16 + q * 4 + r;
            float* op = out_e + (size_t)(e0 + row) * H;
            #pragma unroll
            for (int jt = 0; jt < 4; ++jt) {
                int c = jt * 16 + i;
                float v = (acc[mtl][jt][r] - mu) * rs * egc[jt] + ebtc[jt];
                op[c] = v;
                A[row][c] = f2b(v);
            }
        }

    // ---- stage 3: t1 = gelu(en@n1W1b + Pn1[col]) ----
    zacc(); mm(Wt + 8192);
    #pragma unroll
    for (int mtl = 0; mtl < 2; ++mtl)
        #pragma unroll
        for (int r = 0; r < 4; ++r) {
            int rr = mtl * 4 + r;
            int row = r0 + mtl * 16 + q * 4 + r;
            const ushort* np = (const ushort*)&nv[rr];
            #pragma unroll
            for (int jt = 0; jt < 4; ++jt) {
                int c = jt * 16 + i;
                float v = acc[mtl][jt][r] + b2f(np[jt]);
                A[row][c] = f2b(gelu_f(v));
            }
        }

    // ---- stage 4: msg = LN(gelu(t1@n1W2 + n1b2))*n1g + n1bt ; scatter ----
    zacc(); mm(Wt + 12288);
    #pragma unroll
    for (int mtl = 0; mtl < 2; ++mtl)
        #pragma unroll
        for (int jt = 0; jt < 4; ++jt)
            #pragma unroll
            for (int r = 0; r < 4; ++r)
                acc[mtl][jt][r] = gelu_f(acc[mtl][jt][r] + nb2c[jt]);
    #pragma unroll
    for (int mtl = 0; mtl < 2; ++mtl)
        #pragma unroll
        for (int r = 0; r < 4; ++r) {
            float s = 0.f, ss = 0.f;
            #pragma unroll
            for (int jt = 0; jt < 4; ++jt) { float v = acc[mtl][jt][r]; s += v; ss += v * v; }
            #pragma unroll
            for (int off = 1; off < 16; off <<= 1) {
                s += __shfl_xor(s, off, 64);
                ss += __shfl_xor(ss, off, 64);
            }
            float mu = s * 0.015625f;
            float rs = rsqrtf(ss * 0.015625f - mu * mu + 1e-5f);
            int rbase = rb[mtl * 4 + r];
            #pragma unroll
            for (int jt = 0; jt < 4; ++jt) {
                int c = jt * 16 + i;
                float v = (acc[mtl][jt][r] - mu) * rs * ngc[jt] + nbtc[jt];
                atomicAdd(&agg[rbase + c], v);
            }
        }
}

// ---------------------------------------------------------------------------
// Kernel D: node update + scatter into global sums (segmented reduction).
// ---------------------------------------------------------------------------
__global__ __launch_bounds__(256) void node_kernel(
    const float* __restrict__ agg_sum, const float* __restrict__ deg,
    const int* __restrict__ batch, const float* __restrict__ U_n2,
    const float* __restrict__ n2W1a, const float* __restrict__ n2W2,
    const float* __restrict__ n2b2, const float* __restrict__ n2g,
    const float* __restrict__ n2beta,
    float* __restrict__ out_x, float* __restrict__ g_sum,
    float* __restrict__ g_cnt) {
    __shared__ __align__(16) float in_m[TM * LDSP];
    __shared__ int bIdx[TM];
    int tid = threadIdx.x;
    int n0 = blockIdx.x * TM;
    int tx = tid & 15, ty = tid >> 4;
    int m0 = ty * 4, j0 = tx * 4;
    int valid = NN - n0; if (valid > TM) valid = TM;

    if (tid < TM) {
        int n = n0 + tid;
        bIdx[tid] = (n < NN) ? batch[n] : 0;
    }
    #pragma unroll
    for (int i = 0; i < 4; ++i) {
        int m = i * 16 + ty;
        int k = tx * 4;
        int n = n0 + m;
        float4 v = make_float4(0.f, 0.f, 0.f, 0.f);
        if (n < NN) {
            v = *(const float4*)(agg_sum + (size_t)n * H + k);
            float inv = 1.0f / fmaxf(deg[n], 1.0f);
            v.x *= inv; v.y *= inv; v.z *= inv; v.w *= inv;
        }
        *(float4*)(in_m + m * LDSP + k) = v;
    }
    __syncthreads();

    float acc[4][4];
    zero_acc(acc);
    gemm_tile(n2W1a, in_m, acc, m0, j0);
    #pragma unroll
    for (int mi = 0; mi < 4; ++mi) {
        float4 ue = *(const float4*)(U_n2 + bIdx[m0 + mi] * H + j0);
        acc[mi][0] = gelu_f(acc[mi][0] + ue.x);
        acc[mi][1] = gelu_f(acc[mi][1] + ue.y);
        acc[mi][2] = gelu_f(acc[mi][2] + ue.z);
        acc[mi][3] = gelu_f(acc[mi][3] + ue.w);
    }
    __syncthreads();
    store_tile_lds(in_m, acc, m0, j0);
    __syncthreads();

    zero_acc(acc);
    gemm_tile(n2W2, in_m, acc, m0, j0);
    {
        float4 b4 = *(const float4*)(n2b2 + j0);
        float bb[4] = {b4.x, b4.y, b4.z, b4.w};
        #pragma unroll
        for (int mi = 0; mi < 4; ++mi)
            #pragma unroll
            for (int ji = 0; ji < 4; ++ji)
                acc[mi][ji] = gelu_f(acc[mi][ji] + bb[ji]);
    }
    layernorm_rows(acc, n2g, n2beta, j0);
    #pragma unroll
    for (int mi = 0; mi < 4; ++mi) {
        int n = n0 + m0 + mi;
        if (n < NN) {
            *(float4*)(out_x + (size_t)n * H + j0) =
                make_float4(acc[mi][0], acc[mi][1], acc[mi][2], acc[mi][3]);
        }
    }

    // ---- per-block segmented reduction into g_sum / g_cnt ----
    int b_lo = bIdx[0];
    int b_hi = bIdx[valid - 1];
    for (int b = b_lo; b <= b_hi; ++b) {
        float p0 = 0.f, p1 = 0.f, p2 = 0.f, p3 = 0.f;
        #pragma unroll
        for (int mi = 0; mi < 4; ++mi) {
            int m = m0 + mi;
            if (m < valid && bIdx[m] == b) {
                p0 += acc[mi][0]; p1 += acc[mi][1];
                p2 += acc[mi][2]; p3 += acc[mi][3];
            }
        }
        __syncthreads();   // previous users of in_m (gemm reads / prior b reads) done
        *(float4*)(in_m + ty * LDSP + j0) = make_float4(p0, p1, p2, p3);
        __syncthreads();
        if (tid < H) {
            float s = 0.f;
            #pragma unroll
            for (int r = 0; r < 16; ++r) s += in_m[r * LDSP + tid];
            atomicAdd(&g_sum[(size_t)b * H + tid], s);
        } else if (tid == H) {
            int c = 0;
            for (int m = 0; m < valid; ++m) c += (bIdx[m] == b) ? 1 : 0;
            atomicAdd(&g_cnt[b], (float)c);
        }
    }
}

// ---------------------------------------------------------------------------
// Kernel E: global model (single block)
// ---------------------------------------------------------------------------
__global__ __launch_bounds__(256) void global_kernel(
    const float* __restrict__ u, const float* __restrict__ g_sum,
    const float* __restrict__ g_cnt,
    const float* __restrict__ gW1, const float* __restrict__ gb1,
    const float* __restrict__ gW2, const float* __restrict__ gb2,
    const float* __restrict__ gg, const float* __restrict__ gbeta,
    float* __restrict__ out_u) {
    __shared__ __align__(16) float in_m[TM * LDSP];
    int tid = threadIdx.x;
    int tx = tid & 15, ty = tid >> 4;
    int m0 = ty * 4, j0 = tx * 4;

    #pragma unroll
    for (int i = 0; i < 4; ++i) {
        int m = i * 16 + ty;
        int k = tx * 4;
        *(float4*)(in_m + m * LDSP + k) = *(const float4*)(u + m * H + k);
    }
    __syncthreads();

    float acc[4][4];
    zero_acc(acc);
    gemm_tile(gW1, in_m, acc, m0, j0);
    __syncthreads();
    #pragma unroll
    for (int i = 0; i < 4; ++i) {
        int m = i * 16 + ty;
        int k = tx * 4;
        float4 v = *(const float4*)(g_sum + m * H + k);
        float inv = 1.0f / fmaxf(g_cnt[m], 1.0f);
        v.x *= inv; v.y *= inv; v.z *= inv; v.w *= inv;
        *(float4*)(in_m + m * LDSP + k) = v;
    }
    __syncthreads();
    gemm_tile(gW1 + 64 * H, in_m, acc, m0, j0);
    {
        float4 b4 = *(const float4*)(gb1 + j0);
        float bb[4] = {b4.x, b4.y, b4.z, b4.w};
        #pragma unroll
        for (int mi = 0; mi < 4; ++mi)
            #pragma unroll
            for (int ji = 0; ji < 4; ++ji)
                acc[mi][ji] = gelu_f(acc[mi][ji] + bb[ji]);
    }
    __syncthreads();
    store_tile_lds(in_m, acc, m0, j0);
    __syncthreads();

    zero_acc(acc);
    gemm_tile(gW2, in_m, acc, m0, j0);
    {
        float4 b4 = *(const float4*)(gb2 + j0);
        float bb[4] = {b4.x, b4.y, b4.z, b4.w};
        #pragma unroll
        for (int mi = 0; mi < 4; ++mi)
            #pragma unroll
            for (int ji = 0; ji < 4; ++ji)
                acc[mi][ji] = gelu_f(acc[mi][ji] + bb[ji]);
    }
    layernorm_rows(acc, gg, gbeta, j0);
    #pragma unroll
    for (int mi = 0; mi < 4; ++mi)
        *(float4*)(out_u + (m0 + mi) * H + j0) =
            make_float4(acc[mi][0], acc[mi][1], acc[mi][2], acc[mi][3]);
}

// ---------------------------------------------------------------------------
extern "C" void kernel_launch(void* const* d_in, const int* in_sizes, int n_in,
                              void* d_out, int out_size, void* d_ws, size_t ws_size,
                              hipStream_t stream) {
    const float* x         = (const float*)d_in[0];
    const int*   ei        = (const int*)d_in[1];
    const float* edge_attr = (const float*)d_in[2];
    const float* u         = (const float*)d_in[3];
    const int*   batch     = (const int*)d_in[4];
    const float* eW1 = (const float*)d_in[5];
    const float* eb1 = (const float*)d_in[6];
    const float* eW2 = (const float*)d_in[7];
    const float* eb2 = (const float*)d_in[8];
    const float* eg  = (const float*)d_in[9];
    const float* ebt = (const float*)d_in[10];
    const float* n1W1 = (const float*)d_in[11];
    const float* n1b1 = (const float*)d_in[12];
    const float* n1W2 = (const float*)d_in[13];
    const float* n1b2 = (const float*)d_in[14];
    const float* n1g  = (const float*)d_in[15];
    const float* n1bt = (const float*)d_in[16];
    const float* n2W1 = (const float*)d_in[17];
    const float* n2b1 = (const float*)d_in[18];
    const float* n2W2 = (const float*)d_in[19];
    const float* n2b2 = (const float*)d_in[20];
    const float* n2g  = (const float*)d_in[21];
    const float* n2bt = (const float*)d_in[22];
    const float* gW1 = (const float*)d_in[23];
    const float* gb1 = (const float*)d_in[24];
    const float* gW2 = (const float*)d_in[25];
    const float* gb2 = (const float*)d_in[26];
    const float* gg  = (const float*)d_in[27];
    const float* gbt = (const float*)d_in[28];

    ushort* Qb   = (ushort*)d_ws;
    ushort* Pbb  = Qb + (size_t)NN * H;
    ushort* Pn1b = Pbb + (size_t)NN * H;
    ushort* Wt   = Pn1b + (size_t)NN * H;
    float* U_e   = (float*)(Wt + 4 * 4096);
    float* U_n2  = U_e + GG * H;
    float* agg   = U_n2 + GG * H;            // ---- zeroed region starts here
    float* deg   = agg + (size_t)NN * H;
    float* gsum  = deg + NN;
    float* gcnt  = gsum + GG * H;
    size_t zcount = (size_t)NN * H + NN + GG * H + GG;

    hipMemsetAsync(agg, 0, zcount * sizeof(float), stream);

    float* out_x = (float*)d_out;
    float* out_e = out_x + (size_t)NN * H;
    float* out_u = out_e + (size_t)EE * H;

    wprep_kernel<<<4, 256, 0, stream>>>(eW1, eW2, n1W1, n1W2, Wt);
    utab_kernel<<<2, 256, 0, stream>>>(u, eW1, eb1, n2W1, n2b1, U_e, U_n2);
    precompute_kernel<<<(NN + TM - 1) / TM, 256, 0, stream>>>(
        x, batch, eW1, n1W1, n1b1, U_e, Qb, Pbb, Pn1b);
    edge_kernel<<<(EE + EPB - 1) / EPB, 256, 0, stream>>>(
        edge_attr, ei, Qb, Pbb, Pn1b, Wt,
        eb2, eg, ebt, n1b2, n1g, n1bt,
        out_e, agg, deg);
    node_kernel<<<(NN + TM - 1) / TM, 256, 0, stream>>>(
        agg, deg, batch, U_n2, n2W1, n2W2, n2b2, n2g, n2bt,
        out_x, gsum, gcnt);
    global_kernel<<<1, 256, 0, stream>>>(
        u, gsum, gcnt, gW1, gb1, gW2, gb2, gg, gbt, out_u);
}

// Round 4
// 922.272 us; speedup vs baseline: 2.0124x; 1.1259x over previous
//
#include <hip/hip_runtime.h>
#include <math.h>

#define H 64
#define NN 100000
#define EE 1000000
#define GG 64
#define TM 64
#define LDSP 68   // padded fp32 LDS row stride (floats) for non-edge kernels
#define EPB 128   // edges per block in edge_kernel
#define ALD 72    // padded bf16 LDS row stride (ushorts) in edge_kernel

typedef __attribute__((ext_vector_type(8))) short bf8;
typedef __attribute__((ext_vector_type(4))) float f32x4;

// ---------------------------------------------------------------------------
// helpers
// ---------------------------------------------------------------------------
// Branch-free GELU: 0.5*v*(1+erf(v/sqrt(2))) with A&S 7.1.26 erf
// (|err| <= 1.5e-7, negligible vs bf16 tolerance).  Uses HW v_rcp/v_exp
// (v_exp_f32 computes 2^x) -> ~12 VALU instrs, no divergence, vs ~35+ for
// branchy libm erff.  v*erf(v/√2) == |v|*erf(|v|/√2) since erf is odd.
__device__ __forceinline__ float gelu_f(float v) {
    float a  = fabsf(v);
    float z  = a * 0.70710678118654752440f;
    float d  = fmaf(0.3275911f, z, 1.0f);
    float t;
    asm("v_rcp_f32 %0, %1" : "=v"(t) : "v"(d));
    float p  = t * fmaf(t, fmaf(t, fmaf(t, fmaf(t, 1.061405429f, -1.453152027f),
                                        1.421413741f), -0.284496736f), 0.254829592f);
    float zz = z * z * -1.44269504088896340736f;   // -z^2 * log2(e)
    float e;
    asm("v_exp_f32 %0, %1" : "=v"(e) : "v"(zz));   // exp(-z^2)
    float er = fmaf(-p, e, 1.0f);                  // erf(z), z >= 0
    return fmaf(0.5f * a, er, 0.5f * v);
}

__device__ __forceinline__ unsigned short f2b(float f) {
    union { float f; unsigned int i; } x; x.f = f;
    unsigned int r = x.i + 0x7FFFu + ((x.i >> 16) & 1u);  // RNE
    return (unsigned short)(r >> 16);
}

__device__ __forceinline__ float b2f(unsigned short u) {
    union { unsigned int i; float f; } x; x.i = ((unsigned int)u) << 16; return x.f;
}

__device__ __forceinline__ void zero_acc(float acc[4][4]) {
    #pragma unroll
    for (int i = 0; i < 4; ++i)
        #pragma unroll
        for (int j = 0; j < 4; ++j) acc[i][j] = 0.0f;
}

// fp32 VALU GEMM tile; W may point to global or LDS (inlined -> addrspace
// inferred, LDS path emits ds_read_b128).  W stride is H.
__device__ __forceinline__ void gemm_tile(const float* __restrict__ W,
                                          const float* in_m,
                                          float acc[4][4], int m0, int j0) {
    #pragma unroll 4
    for (int k0 = 0; k0 < H; k0 += 4) {
        float4 A[4], B[4];
        #pragma unroll
        for (int mi = 0; mi < 4; ++mi)
            A[mi] = *(const float4*)(in_m + (m0 + mi) * LDSP + k0);
        #pragma unroll
        for (int kk = 0; kk < 4; ++kk)
            B[kk] = *(const float4*)(W + (k0 + kk) * H + j0);
        #pragma unroll
        for (int mi = 0; mi < 4; ++mi) {
            acc[mi][0] += A[mi].x * B[0].x + A[mi].y * B[1].x + A[mi].z * B[2].x + A[mi].w * B[3].x;
            acc[mi][1] += A[mi].x * B[0].y + A[mi].y * B[1].y + A[mi].z * B[2].y + A[mi].w * B[3].y;
            acc[mi][2] += A[mi].x * B[0].z + A[mi].y * B[1].z + A[mi].z * B[2].z + A[mi].w * B[3].z;
            acc[mi][3] += A[mi].x * B[0].w + A[mi].y * B[1].w + A[mi].z * B[2].w + A[mi].w * B[3].w;
        }
    }
}

__device__ __forceinline__ void store_tile_lds(float* in_m, const float acc[4][4],
                                               int m0, int j0) {
    #pragma unroll
    for (int mi = 0; mi < 4; ++mi)
        *(float4*)(in_m + (m0 + mi) * LDSP + j0) =
            make_float4(acc[mi][0], acc[mi][1], acc[mi][2], acc[mi][3]);
}

// cooperative 64x64 fp32 weight block -> LDS (16 KB), 4 float4 per thread
__device__ __forceinline__ void stage_w(float* Wl, const float* __restrict__ Wsrc,
                                        int tid) {
    #pragma unroll
    for (int p = 0; p < 4; ++p) {
        int idx = p * 1024 + tid * 4;
        *(float4*)(Wl + idx) = *(const float4*)(Wsrc + idx);
    }
}

__device__ __forceinline__ void layernorm_rows(float acc[4][4],
                                               const float* __restrict__ g,
                                               const float* __restrict__ beta,
                                               int j0) {
    float4 g4 = *(const float4*)(g + j0);
    float4 b4 = *(const float4*)(beta + j0);
    float gj[4] = {g4.x, g4.y, g4.z, g4.w};
    float bj[4] = {b4.x, b4.y, b4.z, b4.w};
    #pragma unroll
    for (int mi = 0; mi < 4; ++mi) {
        float s = 0.f, q = 0.f;
        #pragma unroll
        for (int ji = 0; ji < 4; ++ji) { float v = acc[mi][ji]; s += v; q += v * v; }
        #pragma unroll
        for (int off = 1; off < 16; off <<= 1) {
            s += __shfl_xor(s, off, 64);
            q += __shfl_xor(q, off, 64);
        }
        float mu = s * (1.0f / 64.0f);
        float var = q * (1.0f / 64.0f) - mu * mu;
        float rs = rsqrtf(var + 1e-5f);
        #pragma unroll
        for (int ji = 0; ji < 4; ++ji)
            acc[mi][ji] = (acc[mi][ji] - mu) * rs * gj[ji] + bj[ji];
    }
}

// ---------------------------------------------------------------------------
// Weight prep: transpose 4 edge-pipeline weight blocks to bf16 Wt[j][k]
// ---------------------------------------------------------------------------
__global__ __launch_bounds__(256) void wprep_kernel(
    const float* __restrict__ eW1, const float* __restrict__ eW2,
    const float* __restrict__ n1W1, const float* __restrict__ n1W2,
    ushort* __restrict__ Wt) {
    int s = blockIdx.x;
    const float* src = (s == 0) ? (eW1 + 128 * H)
                     : (s == 1) ? eW2
                     : (s == 2) ? (n1W1 + 64 * H) : n1W2;
    int tid = threadIdx.x;
    #pragma unroll
    for (int p = 0; p < 16; ++p) {
        int idx = p * 256 + tid;
        int j = idx >> 6, k = idx & 63;
        Wt[s * 4096 + j * 64 + k] = f2b(src[k * H + j]);
    }
}

// ---------------------------------------------------------------------------
// Kernel B: per-graph tables  U_e = u@eW1[192:256] + eb1 ; U_n2 = u@n2W1[64:128] + n2b1
// ---------------------------------------------------------------------------
__global__ __launch_bounds__(256) void utab_kernel(
    const float* __restrict__ u,
    const float* __restrict__ eW1, const float* __restrict__ eb1,
    const float* __restrict__ n2W1, const float* __restrict__ n2b1,
    float* __restrict__ U_e, float* __restrict__ U_n2) {
    const float* W = (blockIdx.x == 0) ? (eW1 + 192 * H) : (n2W1 + 64 * H);
    const float* b = (blockIdx.x == 0) ? eb1 : n2b1;
    float* out = (blockIdx.x == 0) ? U_e : U_n2;
    int tid = threadIdx.x;
    for (int p = 0; p < 16; ++p) {
        int idx = p * 256 + tid;
        int g = idx >> 6, j = idx & 63;
        float s = b[j];
        for (int k = 0; k < H; ++k) s += u[g * H + k] * W[k * H + j];
        out[idx] = s;
    }
}

// ---------------------------------------------------------------------------
// Kernel A: per-node tables (bf16 outputs), PERMUTED layout:
//   table[node][ (c&15)*4 + (c>>4) ] = value at original column c.
// Weights staged through LDS (one 16KB block at a time) so the inner GEMM
// reads LDS instead of re-fetching L2 per k-step.
// ---------------------------------------------------------------------------
__global__ __launch_bounds__(256) void precompute_kernel(
    const float* __restrict__ x, const int* __restrict__ batch,
    const float* __restrict__ eW1, const float* __restrict__ n1W1,
    const float* __restrict__ n1b1, const float* __restrict__ U_e,
    ushort* __restrict__ Qb, ushort* __restrict__ Pbb,
    ushort* __restrict__ Pn1b) {
    __shared__ __align__(16) float in_m[TM * LDSP];
    __shared__ __align__(16) float Wl[64 * H];
    __shared__ int bIdx[TM];
    int tid = threadIdx.x;
    int n0 = blockIdx.x * TM;
    int tx = tid & 15, ty = tid >> 4;
    int m0 = ty * 4, j0 = tx * 4;

    #pragma unroll
    for (int i = 0; i < 4; ++i) {
        int m = i * 16 + ty;
        int k = tx * 4;
        int n = n0 + m;
        float4 v = make_float4(0.f, 0.f, 0.f, 0.f);
        if (n < NN) v = *(const float4*)(x + (size_t)n * H + k);
        *(float4*)(in_m + m * LDSP + k) = v;
    }
    if (tid < TM) {
        int n = n0 + tid;
        bIdx[tid] = (n < NN) ? batch[n] : 0;
    }
    stage_w(Wl, eW1, tid);
    __syncthreads();

    // permuted position for original column c
    auto pp = [](int c) { return ((c & 15) << 2) | (c >> 4); };

    float acc[4][4];
    // Q
    zero_acc(acc);
    gemm_tile(Wl, in_m, acc, m0, j0);
    #pragma unroll
    for (int mi = 0; mi < 4; ++mi) {
        int n = n0 + m0 + mi;
        if (n < NN) {
            float4 ue = *(const float4*)(U_e + bIdx[m0 + mi] * H + j0);
            float uearr[4] = {ue.x, ue.y, ue.z, ue.w};
            #pragma unroll
            for (int ji = 0; ji < 4; ++ji)
                Qb[(size_t)n * H + pp(j0 + ji)] = f2b(acc[mi][ji] + uearr[ji]);
        }
    }
    __syncthreads();
    stage_w(Wl, eW1 + 64 * H, tid);
    __syncthreads();
    // Pb
    zero_acc(acc);
    gemm_tile(Wl, in_m, acc, m0, j0);
    #pragma unroll
    for (int mi = 0; mi < 4; ++mi) {
        int n = n0 + m0 + mi;
        if (n < NN) {
            #pragma unroll
            for (int ji = 0; ji < 4; ++ji)
                Pbb[(size_t)n * H + pp(j0 + ji)] = f2b(acc[mi][ji]);
        }
    }
    __syncthreads();
    stage_w(Wl, n1W1, tid);
    __syncthreads();
    // Pn1
    zero_acc(acc);
    gemm_tile(Wl, in_m, acc, m0, j0);
    {
        float4 b4 = *(const float4*)(n1b1 + j0);
        float bb[4] = {b4.x, b4.y, b4.z, b4.w};
        #pragma unroll
        for (int mi = 0; mi < 4; ++mi) {
            int n = n0 + m0 + mi;
            if (n < NN) {
                #pragma unroll
                for (int ji = 0; ji < 4; ++ji)
                    Pn1b[(size_t)n * H + pp(j0 + ji)] = f2b(acc[mi][ji] + bb[ji]);
            }
        }
    }
}

// ---------------------------------------------------------------------------
// Kernel C: fused per-edge pipeline, bf16 MFMA version.
// 128 edges/block, 4 waves; wave w owns rows [32w,32w+32) and all 64 cols.
// No __syncthreads anywhere: each wave only touches its own LDS rows.
// Gathers of the permuted node tables are issued as ushort4 row-loads,
// software-pipelined ahead of the MFMA stages that hide their latency.
// Staging uses HW v_cvt_pk_bf16_f32 (2 f32 -> packed 2xbf16 per instr).
// ---------------------------------------------------------------------------
__global__ __launch_bounds__(256) void edge_kernel(
    const float* __restrict__ edge_attr, const int* __restrict__ ei,
    const ushort* __restrict__ Qb, const ushort* __restrict__ Pbb,
    const ushort* __restrict__ Pn1b, const ushort* __restrict__ Wt,
    const float* __restrict__ eb2, const float* __restrict__ eg,
    const float* __restrict__ ebt,
    const float* __restrict__ n1b2, const float* __restrict__ n1g,
    const float* __restrict__ n1bt,
    float* __restrict__ out_e, float* __restrict__ agg,
    float* __restrict__ deg) {
    __shared__ ushort A[EPB][ALD];
    const int tid = threadIdx.x;
    const int w = tid >> 6;
    const int l = tid & 63;
    const int q = l >> 4;
    const int i = l & 15;
    const int r0 = w * 32;                       // wave's row base in block
    const long long e0 = (long long)blockIdx.x * EPB;
    if (e0 + r0 >= EE) return;                   // EE % 32 == 0: wave-granular tail

    // ---- vectorized index loads ----
    int rb[8], cb[8];
    {
        int4 ra0 = *(const int4*)(ei + e0 + r0 + q * 4);
        int4 ra1 = *(const int4*)(ei + e0 + r0 + 16 + q * 4);
        int4 ca0 = *(const int4*)(ei + EE + e0 + r0 + q * 4);
        int4 ca1 = *(const int4*)(ei + EE + e0 + r0 + 16 + q * 4);
        rb[0] = ra0.x << 6; rb[1] = ra0.y << 6; rb[2] = ra0.z << 6; rb[3] = ra0.w << 6;
        rb[4] = ra1.x << 6; rb[5] = ra1.y << 6; rb[6] = ra1.z << 6; rb[7] = ra1.w << 6;
        cb[0] = ca0.x << 6; cb[1] = ca0.y << 6; cb[2] = ca0.z << 6; cb[3] = ca0.w << 6;
        cb[4] = ca1.x << 6; cb[5] = ca1.y << 6; cb[6] = ca1.z << 6; cb[7] = ca1.w << 6;
    }

    // ---- stage edge_attr rows [r0, r0+32) into LDS as bf16 (cvt_pk) ----
    #pragma unroll
    for (int t = 0; t < 4; ++t) {
        int linear = t * 512 + l * 8;            // 0..2047
        int row = linear >> 6;                   // 0..31
        int col = linear & 63;                   // multiple of 8
        const float* sp = edge_attr + (size_t)(e0 + r0 + row) * H + col;
        float4 v0 = *(const float4*)sp;
        float4 v1 = *(const float4*)(sp + 4);
        unsigned int w0, w1, w2, w3;
        asm("v_cvt_pk_bf16_f32 %0, %1, %2" : "=v"(w0) : "v"(v0.x), "v"(v0.y));
        asm("v_cvt_pk_bf16_f32 %0, %1, %2" : "=v"(w1) : "v"(v0.z), "v"(v0.w));
        asm("v_cvt_pk_bf16_f32 %0, %1, %2" : "=v"(w2) : "v"(v1.x), "v"(v1.y));
        asm("v_cvt_pk_bf16_f32 %0, %1, %2" : "=v"(w3) : "v"(v1.z), "v"(v1.w));
        *(uint4*)(&A[r0 + row][col]) = make_uint4(w0, w1, w2, w3);
    }

    // ---- prefetch stage-1 table rows (permuted: ushort4 per row per table) ----
    ushort4 qv[8], pv[8];
    #pragma unroll
    for (int rr = 0; rr < 8; ++rr) {
        qv[rr] = *(const ushort4*)(Qb + rb[rr] + i * 4);
        pv[rr] = *(const ushort4*)(Pbb + cb[rr] + i * 4);
    }

    if (l < 32) atomicAdd(&deg[ei[e0 + r0 + l]], 1.0f);

    // ---- per-lane bias/gain columns (cols jt*16+i) ----
    float eb2c[4], egc[4], ebtc[4], nb2c[4], ngc[4], nbtc[4];
    #pragma unroll
    for (int jt = 0; jt < 4; ++jt) {
        int c = jt * 16 + i;
        eb2c[jt] = eb2[c]; egc[jt] = eg[c]; ebtc[jt] = ebt[c];
        nb2c[jt] = n1b2[c]; ngc[jt] = n1g[c]; nbtc[jt] = n1bt[c];
    }

    f32x4 acc[2][4];
    auto zacc = [&]() {
        #pragma unroll
        for (int m = 0; m < 2; ++m)
            #pragma unroll
            for (int jt = 0; jt < 4; ++jt)
                acc[m][jt] = (f32x4){0.f, 0.f, 0.f, 0.f};
    };
    auto mm = [&](const ushort* Ws) {
        #pragma unroll
        for (int kb = 0; kb < 2; ++kb) {
            bf8 af0 = *(const bf8*)(&A[r0 + i][kb * 32 + q * 8]);
            bf8 af1 = *(const bf8*)(&A[r0 + 16 + i][kb * 32 + q * 8]);
            #pragma unroll
            for (int jt = 0; jt < 4; ++jt) {
                bf8 bf = *(const bf8*)(Ws + (jt * 16 + i) * 64 + kb * 32 + q * 8);
                acc[0][jt] = __builtin_amdgcn_mfma_f32_16x16x32_bf16(af0, bf, acc[0][jt], 0, 0, 0);
                acc[1][jt] = __builtin_amdgcn_mfma_f32_16x16x32_bf16(af1, bf, acc[1][jt], 0, 0, 0);
            }
        }
    };

    // ---- stage 1: h1 = gelu(ea@W1c + Q[row] + Pb[col]) ----
    zacc(); mm(Wt);
    #pragma unroll
    for (int mtl = 0; mtl < 2; ++mtl)
        #pragma unroll
        for (int r = 0; r < 4; ++r) {
            int rr = mtl * 4 + r;
            int row = r0 + mtl * 16 + q * 4 + r;
            const ushort* qp = (const ushort*)&qv[rr];
            const ushort* pb = (const ushort*)&pv[rr];
            #pragma unroll
            for (int jt = 0; jt < 4; ++jt) {
                int c = jt * 16 + i;
                float v = acc[mtl][jt][r] + b2f(qp[jt]) + b2f(pb[jt]);
                A[row][c] = f2b(gelu_f(v));
            }
        }

    // ---- prefetch stage-3 table rows; hidden under stage-2 mm + LN ----
    ushort4 nv[8];
    #pragma unroll
    for (int rr = 0; rr < 8; ++rr)
        nv[rr] = *(const ushort4*)(Pn1b + cb[rr] + i * 4);

    // ---- stage 2: en = LN(gelu(h1@eW2 + eb2))*eg + ebt ; write out_e ----
    zacc(); mm(Wt + 4096);
    #pragma unroll
    for (int mtl = 0; mtl < 2; ++mtl)
        #pragma unroll
        for (int jt = 0; jt < 4; ++jt)
            #pragma unroll
            for (int r = 0; r < 4; ++r)
                acc[mtl][jt][r] = gelu_f(acc[mtl][jt][r] + eb2c[jt]);
    #pragma unroll
    for (int mtl = 0; mtl < 2; ++mtl)
        #pragma unroll
        for (int r = 0; r < 4; ++r) {
            float s = 0.f, ss = 0.f;
            #pragma unroll
            for (int jt = 0; jt < 4; ++jt) { float v = acc[mtl][jt][r]; s += v; ss += v * v; }
            #pragma unroll
            for (int off = 1; off < 16; off <<= 1) {
                s += __shfl_xor(s, off, 64);
                ss += __shfl_xor(ss, off, 64);
            }
            float mu = s * 0.015625f;
            float rs = rsqrtf(ss * 0.015625f - mu * mu + 1e-5f);
            int row = r0 + mtl * 16 + q * 4 + r;
            float* op = out_e + (size_t)(e0 + row) * H;
            #pragma unroll
            for (int jt = 0; jt < 4; ++jt) {
                int c = jt * 16 + i;
                float v = (acc[mtl][jt][r] - mu) * rs * egc[jt] + ebtc[jt];
                op[c] = v;
                A[row][c] = f2b(v);
            }
        }

    // ---- stage 3: t1 = gelu(en@n1W1b + Pn1[col]) ----
    zacc(); mm(Wt + 8192);
    #pragma unroll
    for (int mtl = 0; mtl < 2; ++mtl)
        #pragma unroll
        for (int r = 0; r < 4; ++r) {
            int rr = mtl * 4 + r;
            int row = r0 + mtl * 16 + q * 4 + r;
            const ushort* np = (const ushort*)&nv[rr];
            #pragma unroll
            for (int jt = 0; jt < 4; ++jt) {
                int c = jt * 16 + i;
                float v = acc[mtl][jt][r] + b2f(np[jt]);
                A[row][c] = f2b(gelu_f(v));
            }
        }

    // ---- stage 4: msg = LN(gelu(t1@n1W2 + n1b2))*n1g + n1bt ; scatter ----
    zacc(); mm(Wt + 12288);
    #pragma unroll
    for (int mtl = 0; mtl < 2; ++mtl)
        #pragma unroll
        for (int jt = 0; jt < 4; ++jt)
            #pragma unroll
            for (int r = 0; r < 4; ++r)
                acc[mtl][jt][r] = gelu_f(acc[mtl][jt][r] + nb2c[jt]);
    #pragma unroll
    for (int mtl = 0; mtl < 2; ++mtl)
        #pragma unroll
        for (int r = 0; r < 4; ++r) {
            float s = 0.f, ss = 0.f;
            #pragma unroll
            for (int jt = 0; jt < 4; ++jt) { float v = acc[mtl][jt][r]; s += v; ss += v * v; }
            #pragma unroll
            for (int off = 1; off < 16; off <<= 1) {
                s += __shfl_xor(s, off, 64);
                ss += __shfl_xor(ss, off, 64);
            }
            float mu = s * 0.015625f;
            float rs = rsqrtf(ss * 0.015625f - mu * mu + 1e-5f);
            int rbase = rb[mtl * 4 + r];
            #pragma unroll
            for (int jt = 0; jt < 4; ++jt) {
                int c = jt * 16 + i;
                float v = (acc[mtl][jt][r] - mu) * rs * ngc[jt] + nbtc[jt];
                atomicAdd(&agg[rbase + c], v);
            }
        }
}

// ---------------------------------------------------------------------------
// Kernel D: node update + scatter into global sums (segmented reduction).
// Weights staged through LDS.
// ---------------------------------------------------------------------------
__global__ __launch_bounds__(256) void node_kernel(
    const float* __restrict__ agg_sum, const float* __restrict__ deg,
    const int* __restrict__ batch, const float* __restrict__ U_n2,
    const float* __restrict__ n2W1a, const float* __restrict__ n2W2,
    const float* __restrict__ n2b2, const float* __restrict__ n2g,
    const float* __restrict__ n2beta,
    float* __restrict__ out_x, float* __restrict__ g_sum,
    float* __restrict__ g_cnt) {
    __shared__ __align__(16) float in_m[TM * LDSP];
    __shared__ __align__(16) float Wl[64 * H];
    __shared__ int bIdx[TM];
    int tid = threadIdx.x;
    int n0 = blockIdx.x * TM;
    int tx = tid & 15, ty = tid >> 4;
    int m0 = ty * 4, j0 = tx * 4;
    int valid = NN - n0; if (valid > TM) valid = TM;

    if (tid < TM) {
        int n = n0 + tid;
        bIdx[tid] = (n < NN) ? batch[n] : 0;
    }
    #pragma unroll
    for (int i = 0; i < 4; ++i) {
        int m = i * 16 + ty;
        int k = tx * 4;
        int n = n0 + m;
        float4 v = make_float4(0.f, 0.f, 0.f, 0.f);
        if (n < NN) {
            v = *(const float4*)(agg_sum + (size_t)n * H + k);
            float inv = 1.0f / fmaxf(deg[n], 1.0f);
            v.x *= inv; v.y *= inv; v.z *= inv; v.w *= inv;
        }
        *(float4*)(in_m + m * LDSP + k) = v;
    }
    stage_w(Wl, n2W1a, tid);
    __syncthreads();

    float acc[4][4];
    zero_acc(acc);
    gemm_tile(Wl, in_m, acc, m0, j0);
    #pragma unroll
    for (int mi = 0; mi < 4; ++mi) {
        float4 ue = *(const float4*)(U_n2 + bIdx[m0 + mi] * H + j0);
        acc[mi][0] = gelu_f(acc[mi][0] + ue.x);
        acc[mi][1] = gelu_f(acc[mi][1] + ue.y);
        acc[mi][2] = gelu_f(acc[mi][2] + ue.z);
        acc[mi][3] = gelu_f(acc[mi][3] + ue.w);
    }
    __syncthreads();
    store_tile_lds(in_m, acc, m0, j0);
    stage_w(Wl, n2W2, tid);
    __syncthreads();

    zero_acc(acc);
    gemm_tile(Wl, in_m, acc, m0, j0);
    {
        float4 b4 = *(const float4*)(n2b2 + j0);
        float bb[4] = {b4.x, b4.y, b4.z, b4.w};
        #pragma unroll
        for (int mi = 0; mi < 4; ++mi)
            #pragma unroll
            for (int ji = 0; ji < 4; ++ji)
                acc[mi][ji] = gelu_f(acc[mi][ji] + bb[ji]);
    }
    layernorm_rows(acc, n2g, n2beta, j0);
    #pragma unroll
    for (int mi = 0; mi < 4; ++mi) {
        int n = n0 + m0 + mi;
        if (n < NN) {
            *(float4*)(out_x + (size_t)n * H + j0) =
                make_float4(acc[mi][0], acc[mi][1], acc[mi][2], acc[mi][3]);
        }
    }

    // ---- per-block segmented reduction into g_sum / g_cnt ----
    int b_lo = bIdx[0];
    int b_hi = bIdx[valid - 1];
    for (int b = b_lo; b <= b_hi; ++b) {
        float p0 = 0.f, p1 = 0.f, p2 = 0.f, p3 = 0.f;
        #pragma unroll
        for (int mi = 0; mi < 4; ++mi) {
            int m = m0 + mi;
            if (m < valid && bIdx[m] == b) {
                p0 += acc[mi][0]; p1 += acc[mi][1];
                p2 += acc[mi][2]; p3 += acc[mi][3];
            }
        }
        __syncthreads();   // previous users of in_m done
        *(float4*)(in_m + ty * LDSP + j0) = make_float4(p0, p1, p2, p3);
        __syncthreads();
        if (tid < H) {
            float s = 0.f;
            #pragma unroll
            for (int r = 0; r < 16; ++r) s += in_m[r * LDSP + tid];
            atomicAdd(&g_sum[(size_t)b * H + tid], s);
        } else if (tid == H) {
            int c = 0;
            for (int m = 0; m < valid; ++m) c += (bIdx[m] == b) ? 1 : 0;
            atomicAdd(&g_cnt[b], (float)c);
        }
    }
}

// ---------------------------------------------------------------------------
// Kernel E: global model (single block)
// ---------------------------------------------------------------------------
__global__ __launch_bounds__(256) void global_kernel(
    const float* __restrict__ u, const float* __restrict__ g_sum,
    const float* __restrict__ g_cnt,
    const float* __restrict__ gW1, const float* __restrict__ gb1,
    const float* __restrict__ gW2, const float* __restrict__ gb2,
    const float* __restrict__ gg, const float* __restrict__ gbeta,
    float* __restrict__ out_u) {
    __shared__ __align__(16) float in_m[TM * LDSP];
    int tid = threadIdx.x;
    int tx = tid & 15, ty = tid >> 4;
    int m0 = ty * 4, j0 = tx * 4;

    #pragma unroll
    for (int i = 0; i < 4; ++i) {
        int m = i * 16 + ty;
        int k = tx * 4;
        *(float4*)(in_m + m * LDSP + k) = *(const float4*)(u + m * H + k);
    }
    __syncthreads();

    float acc[4][4];
    zero_acc(acc);
    gemm_tile(gW1, in_m, acc, m0, j0);
    __syncthreads();
    #pragma unroll
    for (int i = 0; i < 4; ++i) {
        int m = i * 16 + ty;
        int k = tx * 4;
        float4 v = *(const float4*)(g_sum + m * H + k);
        float inv = 1.0f / fmaxf(g_cnt[m], 1.0f);
        v.x *= inv; v.y *= inv; v.z *= inv; v.w *= inv;
        *(float4*)(in_m + m * LDSP + k) = v;
    }
    __syncthreads();
    gemm_tile(gW1 + 64 * H, in_m, acc, m0, j0);
    {
        float4 b4 = *(const float4*)(gb1 + j0);
        float bb[4] = {b4.x, b4.y, b4.z, b4.w};
        #pragma unroll
        for (int mi = 0; mi < 4; ++mi)
            #pragma unroll
            for (int ji = 0; ji < 4; ++ji)
                acc[mi][ji] = gelu_f(acc[mi][ji] + bb[ji]);
    }
    __syncthreads();
    store_tile_lds(in_m, acc, m0, j0);
    __syncthreads();

    zero_acc(acc);
    gemm_tile(gW2, in_m, acc, m0, j0);
    {
        float4 b4 = *(const float4*)(gb2 + j0);
        float bb[4] = {b4.x, b4.y, b4.z, b4.w};
        #pragma unroll
        for (int mi = 0; mi < 4; ++mi)
            #pragma unroll
            for (int ji = 0; ji < 4; ++ji)
                acc[mi][ji] = gelu_f(acc[mi][ji] + bb[ji]);
    }
    layernorm_rows(acc, gg, gbeta, j0);
    #pragma unroll
    for (int mi = 0; mi < 4; ++mi)
        *(float4*)(out_u + (m0 + mi) * H + j0) =
            make_float4(acc[mi][0], acc[mi][1], acc[mi][2], acc[mi][3]);
}

// ---------------------------------------------------------------------------
extern "C" void kernel_launch(void* const* d_in, const int* in_sizes, int n_in,
                              void* d_out, int out_size, void* d_ws, size_t ws_size,
                              hipStream_t stream) {
    const float* x         = (const float*)d_in[0];
    const int*   ei        = (const int*)d_in[1];
    const float* edge_attr = (const float*)d_in[2];
    const float* u         = (const float*)d_in[3];
    const int*   batch     = (const int*)d_in[4];
    const float* eW1 = (const float*)d_in[5];
    const float* eb1 = (const float*)d_in[6];
    const float* eW2 = (const float*)d_in[7];
    const float* eb2 = (const float*)d_in[8];
    const float* eg  = (const float*)d_in[9];
    const float* ebt = (const float*)d_in[10];
    const float* n1W1 = (const float*)d_in[11];
    const float* n1b1 = (const float*)d_in[12];
    const float* n1W2 = (const float*)d_in[13];
    const float* n1b2 = (const float*)d_in[14];
    const float* n1g  = (const float*)d_in[15];
    const float* n1bt = (const float*)d_in[16];
    const float* n2W1 = (const float*)d_in[17];
    const float* n2b1 = (const float*)d_in[18];
    const float* n2W2 = (const float*)d_in[19];
    const float* n2b2 = (const float*)d_in[20];
    const float* n2g  = (const float*)d_in[21];
    const float* n2bt = (const float*)d_in[22];
    const float* gW1 = (const float*)d_in[23];
    const float* gb1 = (const float*)d_in[24];
    const float* gW2 = (const float*)d_in[25];
    const float* gb2 = (const float*)d_in[26];
    const float* gg  = (const float*)d_in[27];
    const float* gbt = (const float*)d_in[28];

    ushort* Qb   = (ushort*)d_ws;
    ushort* Pbb  = Qb + (size_t)NN * H;
    ushort* Pn1b = Pbb + (size_t)NN * H;
    ushort* Wt   = Pn1b + (size_t)NN * H;
    float* U_e   = (float*)(Wt + 4 * 4096);
    float* U_n2  = U_e + GG * H;
    float* agg   = U_n2 + GG * H;            // ---- zeroed region starts here
    float* deg   = agg + (size_t)NN * H;
    float* gsum  = deg + NN;
    float* gcnt  = gsum + GG * H;
    size_t zcount = (size_t)NN * H + NN + GG * H + GG;

    hipMemsetAsync(agg, 0, zcount * sizeof(float), stream);

    float* out_x = (float*)d_out;
    float* out_e = out_x + (size_t)NN * H;
    float* out_u = out_e + (size_t)EE * H;

    wprep_kernel<<<4, 256, 0, stream>>>(eW1, eW2, n1W1, n1W2, Wt);
    utab_kernel<<<2, 256, 0, stream>>>(u, eW1, eb1, n2W1, n2b1, U_e, U_n2);
    precompute_kernel<<<(NN + TM - 1) / TM, 256, 0, stream>>>(
        x, batch, eW1, n1W1, n1b1, U_e, Qb, Pbb, Pn1b);
    edge_kernel<<<(EE + EPB - 1) / EPB, 256, 0, stream>>>(
        edge_attr, ei, Qb, Pbb, Pn1b, Wt,
        eb2, eg, ebt, n1b2, n1g, n1bt,
        out_e, agg, deg);
    node_kernel<<<(NN + TM - 1) / TM, 256, 0, stream>>>(
        agg, deg, batch, U_n2, n2W1, n2W2, n2b2, n2g, n2bt,
        out_x, gsum, gcnt);
    global_kernel<<<1, 256, 0, stream>>>(
        u, gsum, gcnt, gW1, gb1, gW2, gb2, gg, gbt, out_u);
}